// Round 9
// baseline (1081.324 us; speedup 1.0000x reference)
//
#include <hip/hip_runtime.h>

using u16 = unsigned short;

typedef __bf16 bf16x8 __attribute__((ext_vector_type(8)));
typedef u16    u16x8  __attribute__((ext_vector_type(8)));
typedef float  f32x4  __attribute__((ext_vector_type(4)));

__device__ __forceinline__ float b2f(u16 u) {
    union { unsigned int i; float f; } c; c.i = ((unsigned int)u) << 16; return c.f;
}
__device__ __forceinline__ u16 f2b(float f) {
    union { float f; unsigned int i; } c; c.f = f;
    unsigned int i = c.i;
    return (u16)((i + 0x7FFFu + ((i >> 16) & 1u)) >> 16);
}
__device__ __forceinline__ unsigned cvtpk(float lo, float hi) {
    unsigned d;
    asm("v_cvt_pk_bf16_f32 %0, %1, %2" : "=v"(d) : "v"(lo), "v"(hi));
    return d;
}

#define AS1 __attribute__((address_space(1)))
#define AS3 __attribute__((address_space(3)))
__device__ __forceinline__ void glds16(const u16* g, u16* l) {
    __builtin_amdgcn_global_load_lds((const AS1 void*)(const void*)g,
                                     (AS3 void*)(void*)l, 16, 0, 0);
}

// ---------------------------------------------------------------------------
// Batched transpose + convert f32 -> bf16: in[b][R][C] f32 -> out[b][C][R] bf16
// ---------------------------------------------------------------------------
__global__ void btrans_f2b(const float* __restrict__ in, u16* __restrict__ out, int R, int C) {
    __shared__ u16 tile[32][33];
    const int c0 = blockIdx.x * 32, r0 = blockIdx.y * 32;
    const size_t base = (size_t)blockIdx.z * R * C;
    const int tx = threadIdx.x, ty = threadIdx.y;
    #pragma unroll
    for (int i = ty; i < 32; i += 8) {
        int r = r0 + i, c = c0 + tx;
        tile[i][tx] = (r < R && c < C) ? f2b(in[base + (size_t)r * C + c]) : (u16)0;
    }
    __syncthreads();
    #pragma unroll
    for (int i = ty; i < 32; i += 8) {
        int c = c0 + i, r = r0 + tx;
        if (c < C && r < R) out[base + (size_t)c * R + r] = tile[tx][i];
    }
}

// Batched transpose + convert bf16 -> f32: in[b][R][C] bf16 -> out[b][C][R] f32
__global__ void btrans_b2f(const u16* __restrict__ in, float* __restrict__ out, int R, int C) {
    __shared__ u16 tile[32][33];
    const int c0 = blockIdx.x * 32, r0 = blockIdx.y * 32;
    const size_t base = (size_t)blockIdx.z * R * C;
    const int tx = threadIdx.x, ty = threadIdx.y;
    #pragma unroll
    for (int i = ty; i < 32; i += 8) {
        int r = r0 + i, c = c0 + tx;
        tile[i][tx] = (r < R && c < C) ? in[base + (size_t)r * C + c] : (u16)0;
    }
    __syncthreads();
    #pragma unroll
    for (int i = ty; i < 32; i += 8) {
        int c = c0 + i, r = r0 + tx;
        if (c < C && r < R) out[base + (size_t)c * R + r] = b2f(tile[tx][i]);
    }
}

// ---------------------------------------------------------------------------
// wtile_f2b: K=256 weight pre-tiling. in: W[256][N] f32 -> out fragment-linear
// bf16 tiles: out[colblk][kt][l16*32 + quad*8 + e] = W[kt*32+quad*8+e][colblk*16+l16].
// Makes gemm_kres's per-wave B-frag loads perfectly coalesced 1KB wave-loads.
// grid: (N/16, 8), 64 threads.
// ---------------------------------------------------------------------------
__global__ void wtile_f2b(const float* __restrict__ in, u16* __restrict__ out, int N) {
    const int lane = threadIdx.x;
    const int colblk = blockIdx.x, kt = blockIdx.y;
    const int l16 = lane & 15, quad = lane >> 4;
    const int col = colblk * 16 + l16;
    u16x8 tmp;
    #pragma unroll
    for (int e = 0; e < 8; e++) {
        const int k = kt * 32 + quad * 8 + e;
        tmp[e] = f2b(in[(size_t)k * N + col]);
    }
    *(u16x8*)&out[(size_t)colblk * 4096 + kt * 512 + l16 * 32 + quad * 8] = tmp;
}

// ---------------------------------------------------------------------------
// gemm_kres: C[M,N] = epilogue(A[M,256] @ B + bias), K=256 FIXED (qkv/proj/W1).
// R12: barrier-free N-sweep design.
//  - A: 64 rows x K=256 staged ONCE in LDS as [kt][64][32] chunks -- identical
//    intra-chunk layout + glds source-swizzle + cfrag read as R9's A buffer
//    (measured 0 bank conflicts). One __syncthreads total.
//  - B: per-wave 32-col panel in registers (2x8 bf16x8 = 64 VGPR), reloaded
//    per sweep from the TILED weight layout (wtile_f2b) -> 16 coalesced 1KB
//    wave-loads from L2-hot weights.
//  - Inner: 8 kt x {4 ds_read_b128 + 8 MFMA}; NO barriers, NO inline waitcnt.
//    Waves free-run; 3 waves/SIMD (cap 170 VGPR) hide L2/LDS latency by TLP.
//  - R10 failure (VGPR remat) fixed by 96-VGPR core; R11 failure (flat-layout
//    bank conflicts) fixed by the chunked proven layout.
// 4 waves/block, wave tile 64x32, block = 64 rows, sweeps over N in 128-col
// steps (wave w owns cols [s*128 + w*32, +32)).
// EPI: 0 = bias only; 1 = bias+residual+RepBN; 2 = bias+SpatialSiLU
// ---------------------------------------------------------------------------
template<int EPI>
__launch_bounds__(256, 3)
__global__ void gemm_kres(const u16* __restrict__ A, const u16* __restrict__ BT,
                          const float* __restrict__ bias, u16* __restrict__ C,
                          int N, int row0,
                          const u16* __restrict__ R0,
                          const float* __restrict__ g, const float* __restrict__ be,
                          const float* __restrict__ rmv, const float* __restrict__ rvv,
                          const float* __restrict__ alpha,
                          const float* __restrict__ saw, const float* __restrict__ sab) {
    __shared__ __align__(16) u16 AL[8][2048];   // [kt][64 rows][32 k] = 32 KB
    const int tid = threadIdx.x, wave = tid >> 6, lane = tid & 63;
    const int quad = lane >> 4, l16 = lane & 15;
    const int m0 = blockIdx.x * 64;

    // ---- stage A once: wave stages chunks kt = wave*2, wave*2+1 ----
    {
        const int srow = lane >> 2;                               // 0..15
        const int scol = (((lane & 3) ^ ((srow >> 1) & 3)) * 8);  // source swizzle
        #pragma unroll
        for (int t = 0; t < 2; t++) {
            const int kt = wave * 2 + t;
            #pragma unroll
            for (int rb = 0; rb < 4; rb++) {
                glds16(A + (size_t)(m0 + rb * 16 + srow) * 256 + kt * 32 + scol,
                       &AL[kt][rb * 512]);
            }
        }
    }
    __syncthreads();   // the ONLY barrier

    const int cfrag = (quad ^ ((l16 >> 1) & 3)) * 8;
    const int dup = l16 & 1, pr = l16 >> 1;
    const float alphav = (EPI == 1) ? alpha[0] : 0.f;

    // EPI=2 block-constant spatial params (<=2 distinct batches per 64 rows)
    float s0w = 0.f, s0b = 0.f, s1w = 0.f, s1b = 0.f; int rowB = 0x7fffffff;
    if (EPI == 2) {
        const int bidx0 = (row0 + m0) / 196;
        const int bi1 = (bidx0 + 1 < 256) ? bidx0 + 1 : 255;
        rowB = (bidx0 + 1) * 196;
        s0w = saw[bidx0]; s0b = sab[bidx0];
        s1w = saw[bi1];   s1b = sab[bi1];
    }

    const int nsweep = N >> 7;
    for (int s = 0; s < nsweep; s++) {
        const int c0 = s * 128 + wave * 32;

        // ---- B panel: 16 coalesced b128 loads from tiled weights ----
        bf16x8 bfr[2][8];
        const u16* bbase = BT + (size_t)(c0 >> 4) * 4096 + l16 * 32 + quad * 8;
        #pragma unroll
        for (int j = 0; j < 2; j++)
            #pragma unroll
            for (int kt = 0; kt < 8; kt++)
                bfr[j][kt] = *(const bf16x8*)(bbase + j * 4096 + kt * 512);

        float biasv[2];
        biasv[0] = bias[c0 + l16];
        biasv[1] = bias[c0 + 16 + l16];
        float k0p[2][2], k1p[2][2];
        if (EPI == 1) {
            #pragma unroll
            for (int j = 0; j < 2; j++)
                #pragma unroll
                for (int p = 0; p < 2; p++) {
                    const int col = c0 + j * 16 + pr * 2 + p;
                    const float sc = g[col] * rsqrtf(rvv[col] + 1e-5f);
                    k1p[j][p] = sc + alphav;
                    k0p[j][p] = be[col] - rmv[col] * sc;
                }
        }

        // ---- K-loop: barrier-free ----
        f32x4 acc[4][2] = {};
        #pragma unroll
        for (int kt = 0; kt < 8; kt++) {
            bf16x8 af[4];
            #pragma unroll
            for (int i = 0; i < 4; i++)
                af[i] = *(const bf16x8*)&AL[kt][(i * 16 + l16) * 32 + cfrag];
            #pragma unroll
            for (int i = 0; i < 4; i++) {
                acc[i][0] = __builtin_amdgcn_mfma_f32_16x16x32_bf16(af[i], bfr[0][kt], acc[i][0], 0, 0, 0);
                acc[i][1] = __builtin_amdgcn_mfma_f32_16x16x32_bf16(af[i], bfr[1][kt], acc[i][1], 0, 0, 0);
            }
        }

        // ---- epilogue: pair-pack + dword stores (wave-private) ----
        const int r0i = 2 * dup, r1i = r0i + 1;
        #pragma unroll
        for (int i = 0; i < 4; i++) {
            #pragma unroll
            for (int j = 0; j < 2; j++) {
                float vv[4];
                #pragma unroll
                for (int r = 0; r < 4; r++) {
                    float v = acc[i][j][r] + biasv[j];
                    if (EPI == 2) {
                        const int rg = row0 + m0 + i * 16 + quad * 4 + r;
                        const bool hb = rg >= rowB;
                        const float w = fmaf(hb ? s1w : s0w, v, hb ? s1b : s0b);
                        v = v / (1.f + __expf(-w * v));
                    }
                    vv[r] = v;
                }
                float ot[4];
                #pragma unroll
                for (int r = 0; r < 4; r++) ot[r] = __shfl_xor(vv[r], 1, 64);
                float lo0 = dup ? ot[r0i] : vv[r0i], hi0 = dup ? vv[r0i] : ot[r0i];
                float lo1 = dup ? ot[r1i] : vv[r1i], hi1 = dup ? vv[r1i] : ot[r1i];
                if (EPI == 1) {
                    const u16* rp = R0 + (size_t)(m0 + i * 16 + quad * 4 + r0i) * N
                                       + (c0 + j * 16 + pr * 2);
                    const unsigned rd0 = *(const unsigned*)rp;
                    const unsigned rd1 = *(const unsigned*)(rp + N);
                    lo0 = fmaf(lo0 + b2f((u16)(rd0 & 0xffff)), k1p[j][0], k0p[j][0]);
                    hi0 = fmaf(hi0 + b2f((u16)(rd0 >> 16)),    k1p[j][1], k0p[j][1]);
                    lo1 = fmaf(lo1 + b2f((u16)(rd1 & 0xffff)), k1p[j][0], k0p[j][0]);
                    hi1 = fmaf(hi1 + b2f((u16)(rd1 >> 16)),    k1p[j][1], k0p[j][1]);
                }
                u16* p = C + (size_t)(m0 + i * 16 + quad * 4 + 2 * dup) * N
                           + (c0 + j * 16 + pr * 2);
                *(unsigned*)p       = cvtpk(lo0, hi0);
                *(unsigned*)(p + N) = cvtpk(lo1, hi1);
            }
        }
    }
}

// ---------------------------------------------------------------------------
// gemm_bt: generic K GEMM (used for W2, K=2048). R9 proven structure.
// EPI: 0 = bias only; 1 = bias+residual+RepBN; 2 = bias+SpatialSiLU
// ---------------------------------------------------------------------------
template<int EPI>
__launch_bounds__(512, 4)
__global__ void gemm_bt(const u16* __restrict__ A, const u16* __restrict__ BT,
                        const float* __restrict__ bias, u16* __restrict__ C,
                        int M, int N, int K, int row0,
                        const u16* __restrict__ R0,
                        const float* __restrict__ g, const float* __restrict__ be,
                        const float* __restrict__ rmv, const float* __restrict__ rvv,
                        const float* __restrict__ alpha,
                        const float* __restrict__ saw, const float* __restrict__ sab) {
    __shared__ __align__(16) u16 SL[24576];  // 48 KB: A 2x8192, B 2x4096
    const int tid  = threadIdx.x;
    const int wave = tid >> 6, lane = tid & 63;
    const int wm = wave >> 1, wn = wave & 1;
    const int quad = lane >> 4, l16 = lane & 15;

    const unsigned gx = gridDim.x;
    unsigned lin = blockIdx.y * gx + blockIdx.x;
    const unsigned nwg = gx * gridDim.y;
    const unsigned q8 = nwg >> 3, r8 = nwg & 7;
    const unsigned xcd = lin & 7, loc = lin >> 3;
    lin = (xcd < r8 ? xcd * (q8 + 1) : r8 * (q8 + 1) + (xcd - r8) * q8) + loc;
    const int m0 = (int)(lin / gx) * 256, n0 = (int)(lin % gx) * 128;

    const int srow = lane >> 2;
    const int scol = (((lane & 3) ^ ((srow >> 1) & 3)) * 8);
    const size_t aoff0 = (size_t)(m0 + wave * 32 + srow) * K + scol;
    const size_t aoff1 = aoff0 + (size_t)16 * K;
    const size_t boff  = (size_t)(n0 + wave * 16 + srow) * K + scol;

    const int cfrag = (quad ^ ((l16 >> 1) & 3)) * 8;

    f32x4 acc[4][4] = {};
    const int niter = K >> 5;

    auto stage = [&](int buf, size_t kn) {
        glds16(A  + aoff0 + kn, SL + buf * 8192 + wave * 1024);
        glds16(A  + aoff1 + kn, SL + buf * 8192 + wave * 1024 + 512);
        glds16(BT + boff  + kn, SL + 16384 + buf * 4096 + wave * 512);
    };

    auto kstep = [&](int cur, int kt) {
        __syncthreads();
        if (kt + 1 < niter) stage(cur ^ 1, (size_t)(kt + 1) << 5);
        const u16* ab = SL + cur * 8192;
        const u16* bb = SL + 16384 + cur * 4096;
        bf16x8 af[4], bfr[4];
        #pragma unroll
        for (int i = 0; i < 4; i++)
            af[i] = *(const bf16x8*)&ab[(wm * 64 + i * 16 + l16) * 32 + cfrag];
        #pragma unroll
        for (int j = 0; j < 4; j++)
            bfr[j] = *(const bf16x8*)&bb[(wn * 64 + j * 16 + l16) * 32 + cfrag];
        #pragma unroll
        for (int i = 0; i < 4; i++)
            #pragma unroll
            for (int j = 0; j < 4; j++)
                acc[i][j] = __builtin_amdgcn_mfma_f32_16x16x32_bf16(af[i], bfr[j], acc[i][j], 0, 0, 0);
    };

    stage(0, 0);
    int kt = 0;
    for (; kt + 2 <= niter; kt += 2) { kstep(0, kt); kstep(1, kt + 1); }
    if (kt < niter) kstep(kt & 1, kt);

    __syncthreads();

    float alphav = 0.f;
    if (EPI == 1) alphav = alpha[0];

    float biasv[4], k0v[4], k1v[4];
    #pragma unroll
    for (int j = 0; j < 4; j++) {
        const int col = n0 + wn * 64 + j * 16 + l16;
        biasv[j] = bias[col];
        if (EPI == 1) {
            float sc = g[col] * rsqrtf(rvv[col] + 1e-5f);
            k1v[j] = sc + alphav;
            k0v[j] = be[col] - rmv[col] * sc;
        }
    }

    const int dup = l16 & 1;
    const int pr  = l16 >> 1;
    u16* Crow = C + (size_t)(m0 + wm * 64 + quad * 4 + 2 * dup) * N
                  + (n0 + wn * 64 + pr * 2);

    auto emit = [&]() {
        #pragma unroll
        for (int i = 0; i < 4; i++) {
            float swv4[4], sbv4[4];
            if (EPI == 2) {
                #pragma unroll
                for (int r = 0; r < 4; r++) {
                    const int row = row0 + m0 + wm * 64 + i * 16 + quad * 4 + r;
                    const int bidx = row / 196;
                    swv4[r] = saw[bidx]; sbv4[r] = sab[bidx];
                }
            }
            #pragma unroll
            for (int j = 0; j < 4; j++) {
                float vv[4];
                #pragma unroll
                for (int r = 0; r < 4; r++) {
                    float v = acc[i][j][r] + biasv[j];
                    if (EPI == 1) {
                        const int rowL = (wm & 1) * 64 + i * 16 + quad * 4 + r;
                        const int colp = wn * 64 + j * 16 + (l16 & ~1);
                        unsigned rd = *(const unsigned*)&SL[rowL * 128 + colp];
                        unsigned fb = dup ? (rd & 0xffff0000u) : (rd << 16);
                        union { unsigned u; float f; } cc; cc.u = fb;
                        float x = v + cc.f;
                        v = fmaf(x, k1v[j], k0v[j]);
                    } else if (EPI == 2) {
                        float w = fmaf(swv4[r], v, sbv4[r]);
                        v = v / (1.f + __expf(-w * v));
                    }
                    vv[r] = v;
                }
                unsigned D[4];
                #pragma unroll
                for (int r = 0; r < 4; r++) {
                    float o  = __shfl_xor(vv[r], 1, 64);
                    float lo = dup ? o : vv[r];
                    float hi = dup ? vv[r] : o;
                    D[r] = cvtpk(lo, hi);
                }
                unsigned s0 = dup ? D[2] : D[0];
                unsigned s1 = dup ? D[3] : D[1];
                u16* p = Crow + (size_t)i * 16 * N + j * 16;
                *(unsigned*)p       = s0;
                *(unsigned*)(p + N) = s1;
            }
        }
    };

    if (EPI == 1) {
        #pragma unroll
        for (int h = 0; h < 2; h++) {
            for (int c = tid; c < 2048; c += 512) {
                int row = c >> 4, colc = (c & 15) * 8;
                *(u16x8*)&SL[row * 128 + colc] =
                    *(const u16x8*)&R0[(size_t)(m0 + h * 128 + row) * N + n0 + colc];
            }
            __syncthreads();
            if ((wm >> 1) == h) emit();
            __syncthreads();
        }
    } else {
        emit();
    }
}

// ---------------------------------------------------------------------------
// MFMA flash attention: one block per (local b, h), 4 waves.
// V staging vectorized (u16x8 row reads + scalar transposed LDS writes).
// ---------------------------------------------------------------------------
__launch_bounds__(256)
__global__ void attn_kernel(const u16* __restrict__ qkv, u16* __restrict__ o) {
    __shared__ __align__(16) u16 Kb[224 * 32];
    __shared__ __align__(16) u16 Vt[32 * 232];
    __shared__ __align__(16) u16 Pl[4][16 * 232];
    const int tid  = threadIdx.x;
    const int wave = tid >> 6, lane = tid & 63;
    const int quad = lane >> 4, l16 = lane & 15;
    const int b = blockIdx.x >> 3, h = blockIdx.x & 7;
    const u16* qg = qkv + (size_t)b * 196 * 768 + h * 32;
    const float scale = 0.17677669529663687f; // 1/sqrt(32)

    for (int idx = tid; idx < 896; idx += 256) {
        int row = idx >> 2, dp = (idx & 3) * 8;
        u16x8 kv = {};
        if (row < 196) kv = *(const u16x8*)&qg[(size_t)row * 768 + 256 + dp];
        *(u16x8*)&Kb[row * 32 + dp] = kv;
    }
    for (int idx = tid; idx < 896; idx += 256) {
        int row = idx >> 2, dp = (idx & 3) * 8;
        u16x8 vv = {};
        if (row < 196) vv = *(const u16x8*)&qg[(size_t)row * 768 + 512 + dp];
        #pragma unroll
        for (int e = 0; e < 8; e++) Vt[(dp + e) * 232 + row] = vv[e];
    }
    for (int c = lane; c < 16 * 24; c += 64) {
        int m = c / 24, cc = 208 + (c % 24);
        Pl[wave][m * 232 + cc] = 0;
    }
    __syncthreads();

    for (int t = wave; t < 13; t += 4) {
        const int m0 = t * 16;
        bf16x8 aq = {};
        const int qrow = m0 + l16;
        if (qrow < 196) aq = *(const bf16x8*)&qg[(size_t)qrow * 768 + quad * 8];

        f32x4 s[13];
        #pragma unroll
        for (int ct = 0; ct < 13; ct++) {
            bf16x8 bk = *(const bf16x8*)&Kb[(ct * 16 + l16) * 32 + quad * 8];
            s[ct] = __builtin_amdgcn_mfma_f32_16x16x32_bf16(aq, bk, (f32x4){0.f, 0.f, 0.f, 0.f}, 0, 0, 0);
        }
        if (l16 >= 4) {
            #pragma unroll
            for (int r = 0; r < 4; r++) s[12][r] = -1e30f;
        }
        float mx[4] = {-1e30f, -1e30f, -1e30f, -1e30f};
        #pragma unroll
        for (int ct = 0; ct < 13; ct++)
            #pragma unroll
            for (int r = 0; r < 4; r++) mx[r] = fmaxf(mx[r], s[ct][r]);
        #pragma unroll
        for (int off = 1; off < 16; off <<= 1)
            #pragma unroll
            for (int r = 0; r < 4; r++) mx[r] = fmaxf(mx[r], __shfl_xor(mx[r], off, 64));
        float sum[4] = {0.f, 0.f, 0.f, 0.f};
        #pragma unroll
        for (int ct = 0; ct < 13; ct++) {
            #pragma unroll
            for (int r = 0; r < 4; r++) {
                float p = __expf((s[ct][r] - mx[r]) * scale);
                sum[r] += p;
                Pl[wave][(quad * 4 + r) * 232 + ct * 16 + l16] = f2b(p);
            }
        }
        #pragma unroll
        for (int off = 1; off < 16; off <<= 1)
            #pragma unroll
            for (int r = 0; r < 4; r++) sum[r] += __shfl_xor(sum[r], off, 64);
        float inv[4];
        #pragma unroll
        for (int r = 0; r < 4; r++) inv[r] = 1.f / sum[r];

        #pragma unroll
        for (int nt = 0; nt < 2; nt++) {
            f32x4 ao = {0.f, 0.f, 0.f, 0.f};
            #pragma unroll
            for (int kc = 0; kc < 7; kc++) {
                bf16x8 ap = *(const bf16x8*)&Pl[wave][l16 * 232 + kc * 32 + quad * 8];
                bf16x8 bv = *(const bf16x8*)&Vt[(nt * 16 + l16) * 232 + kc * 32 + quad * 8];
                ao = __builtin_amdgcn_mfma_f32_16x16x32_bf16(ap, bv, ao, 0, 0, 0);
            }
            #pragma unroll
            for (int r = 0; r < 4; r++) {
                const int gm = m0 + quad * 4 + r;
                if (gm < 196)
                    o[((size_t)b * 196 + gm) * 256 + h * 32 + nt * 16 + l16] = f2b(ao[r] * inv[r]);
            }
        }
    }
}

// ---------------------------------------------------------------------------
extern "C" void kernel_launch(void* const* d_in, const int* in_sizes, int n_in,
                              void* d_out, int out_size, void* d_ws, size_t ws_size,
                              hipStream_t stream) {
    const float* x      = (const float*)d_in[0];
    const float* Wqkv   = (const float*)d_in[1];
    const float* bqkv   = (const float*)d_in[2];
    const float* Wproj  = (const float*)d_in[3];
    const float* bproj  = (const float*)d_in[4];
    const float* W1     = (const float*)d_in[5];
    const float* b1     = (const float*)d_in[6];
    const float* W2     = (const float*)d_in[7];
    const float* b2     = (const float*)d_in[8];
    const float* saw    = (const float*)d_in[9];
    const float* sab    = (const float*)d_in[10];
    const float* alpha1 = (const float*)d_in[11];
    const float* g1     = (const float*)d_in[12];
    const float* be1    = (const float*)d_in[13];
    const float* rm1    = (const float*)d_in[14];
    const float* rv1    = (const float*)d_in[15];
    const float* alpha2 = (const float*)d_in[16];
    const float* g2     = (const float*)d_in[17];
    const float* be2    = (const float*)d_in[18];
    const float* rm2    = (const float*)d_in[19];
    const float* rv2    = (const float*)d_in[20];

    const int B = 256, Cc = 256, Np = 196, CM = 2048;
    const int M = B * Np; // 50176

    auto al = [](size_t s) { return (s + 255) & ~(size_t)255; };
    char* ws = (char*)d_ws;
    const size_t o_t0  = 0;
    const size_t o_t1  = o_t0 + al((size_t)M * Cc * 2);
    const size_t o_wq  = o_t1 + al((size_t)M * Cc * 2);
    const size_t o_wp  = o_wq + al((size_t)768 * Cc * 2);
    const size_t o_w1  = o_wp + al((size_t)Cc * Cc * 2);
    const size_t o_w2  = o_w1 + al((size_t)Cc * CM * 2);
    const size_t o_scr = o_w2 + al((size_t)CM * Cc * 2);
    const size_t S = (ws_size > o_scr) ? ws_size - o_scr : 0;

    u16* t0     = (u16*)(ws + o_t0);
    u16* t1b    = (u16*)(ws + o_t1);
    u16* WqkvT  = (u16*)(ws + o_wq);
    u16* WprojT = (u16*)(ws + o_wp);
    u16* W1T    = (u16*)(ws + o_w1);
    u16* W2T    = (u16*)(ws + o_w2);
    u16* scr    = (u16*)(ws + o_scr);
    u16* t2     = t0;            // alias: t0 dead after proj epilogue
    u16* obuf   = (u16*)d_out;   // bf16 scratch in f32 d_out; fully rewritten by final btrans
    float* out  = (float*)d_out;

    // chunk counts: M-chunks must stay multiples of 256 (gemm_bt W2 tiles).
    int nq = 1; while (nq < 4 && ((size_t)(M / nq) * 768 * 2) > S) nq *= 2;
    const int nf_opts[6] = {1, 2, 4, 14, 28, 56};
    int nf = 56;
    for (int i = 0; i < 6; ++i) {
        if (((size_t)(M / nf_opts[i]) * CM * 2) <= S) { nf = nf_opts[i]; break; }
    }
    const int Mq = M / nq, Bq = B / nq;
    const int Mf = M / nf;

    dim3 tb(32, 8, 1);
    // x f32 [B][C][N] -> t0 bf16 [B][N][C]
    btrans_f2b<<<dim3((Np + 31) / 32, (Cc + 31) / 32, B), tb, 0, stream>>>(x, t0, Cc, Np);
    // K=256 weights -> fragment-tiled bf16 (for gemm_kres coalesced B loads)
    wtile_f2b<<<dim3(768 / 16, 8), 64, 0, stream>>>(Wqkv,  WqkvT,  768);
    wtile_f2b<<<dim3(Cc  / 16, 8), 64, 0, stream>>>(Wproj, WprojT, Cc);
    wtile_f2b<<<dim3(CM  / 16, 8), 64, 0, stream>>>(W1,    W1T,    CM);
    // W2 f32 [CM][Cc] -> row-major bf16 [Cc][CM] for gemm_bt
    btrans_f2b<<<dim3(Cc / 32, CM / 32, 1), tb, 0, stream>>>(W2, W2T, CM, Cc);

    // qkv + attention, chunked over batches (K=256 -> gemm_kres)
    for (int c = 0; c < nq; ++c) {
        gemm_kres<0><<<dim3(Mq / 64), 256, 0, stream>>>(
            t0 + (size_t)c * Mq * Cc, WqkvT, bqkv, scr, 768, 0,
            nullptr, nullptr, nullptr, nullptr, nullptr, nullptr, nullptr, nullptr);
        attn_kernel<<<dim3(Bq * 8), 256, 0, stream>>>(scr, obuf + (size_t)c * Mq * Cc);
    }

    // t1 = RepBN1(t0 + obuf @ Wproj + bproj)  (K=256 -> gemm_kres)
    gemm_kres<1><<<dim3(M / 64), 256, 0, stream>>>(
        obuf, WprojT, bproj, t1b, Cc, 0,
        t0, g1, be1, rm1, rv1, alpha1, nullptr, nullptr);

    // FFN: W1 (K=256 -> gemm_kres), W2 (K=2048 -> gemm_bt)
    for (int c = 0; c < nf; ++c) {
        gemm_kres<2><<<dim3(Mf / 64), 256, 0, stream>>>(
            t1b + (size_t)c * Mf * Cc, W1T, b1, scr, CM, c * Mf,
            nullptr, nullptr, nullptr, nullptr, nullptr, nullptr, saw, sab);
        gemm_bt<1><<<dim3(Cc / 128, Mf / 256), 512, 0, stream>>>(
            scr, W2T, b2, t2 + (size_t)c * Mf * Cc, Mf, Cc, CM, 0,
            t1b + (size_t)c * Mf * Cc, g2, be2, rm2, rv2, alpha2, nullptr, nullptr);
    }

    // t2 bf16 [B][N][C] -> out f32 [B][C][N]
    btrans_b2f<<<dim3((Cc + 31) / 32, (Np + 31) / 32, B), tb, 0, stream>>>(t2, out, Np, Cc);
}

// Round 10
// 650.199 us; speedup vs baseline: 1.6631x; 1.6631x over previous
//
#include <hip/hip_runtime.h>

using u16 = unsigned short;

typedef __bf16 bf16x8 __attribute__((ext_vector_type(8)));
typedef u16    u16x8  __attribute__((ext_vector_type(8)));
typedef float  f32x4  __attribute__((ext_vector_type(4)));

__device__ __forceinline__ float b2f(u16 u) {
    union { unsigned int i; float f; } c; c.i = ((unsigned int)u) << 16; return c.f;
}
__device__ __forceinline__ u16 f2b(float f) {
    union { float f; unsigned int i; } c; c.f = f;
    unsigned int i = c.i;
    return (u16)((i + 0x7FFFu + ((i >> 16) & 1u)) >> 16);
}
__device__ __forceinline__ unsigned cvtpk(float lo, float hi) {
    unsigned d;
    asm("v_cvt_pk_bf16_f32 %0, %1, %2" : "=v"(d) : "v"(lo), "v"(hi));
    return d;
}

#define AS1 __attribute__((address_space(1)))
#define AS3 __attribute__((address_space(3)))
__device__ __forceinline__ void glds16(const u16* g, u16* l) {
    __builtin_amdgcn_global_load_lds((const AS1 void*)(const void*)g,
                                     (AS3 void*)(void*)l, 16, 0, 0);
}

// ---------------------------------------------------------------------------
// Batched transpose + convert f32 -> bf16: in[b][R][C] f32 -> out[b][C][R] bf16
// ---------------------------------------------------------------------------
__global__ void btrans_f2b(const float* __restrict__ in, u16* __restrict__ out, int R, int C) {
    __shared__ u16 tile[32][33];
    const int c0 = blockIdx.x * 32, r0 = blockIdx.y * 32;
    const size_t base = (size_t)blockIdx.z * R * C;
    const int tx = threadIdx.x, ty = threadIdx.y;
    #pragma unroll
    for (int i = ty; i < 32; i += 8) {
        int r = r0 + i, c = c0 + tx;
        tile[i][tx] = (r < R && c < C) ? f2b(in[base + (size_t)r * C + c]) : (u16)0;
    }
    __syncthreads();
    #pragma unroll
    for (int i = ty; i < 32; i += 8) {
        int c = c0 + i, r = r0 + tx;
        if (c < C && r < R) out[base + (size_t)c * R + r] = tile[tx][i];
    }
}

// Batched transpose + convert bf16 -> f32: in[b][R][C] bf16 -> out[b][C][R] f32
__global__ void btrans_b2f(const u16* __restrict__ in, float* __restrict__ out, int R, int C) {
    __shared__ u16 tile[32][33];
    const int c0 = blockIdx.x * 32, r0 = blockIdx.y * 32;
    const size_t base = (size_t)blockIdx.z * R * C;
    const int tx = threadIdx.x, ty = threadIdx.y;
    #pragma unroll
    for (int i = ty; i < 32; i += 8) {
        int r = r0 + i, c = c0 + tx;
        tile[i][tx] = (r < R && c < C) ? in[base + (size_t)r * C + c] : (u16)0;
    }
    __syncthreads();
    #pragma unroll
    for (int i = ty; i < 32; i += 8) {
        int c = c0 + i, r = r0 + tx;
        if (c < C && r < R) out[base + (size_t)c * R + r] = b2f(tile[tx][i]);
    }
}

// ---------------------------------------------------------------------------
// gemm8: 8-phase counted-vmcnt GEMM (T3+T4+T5 per the m201/m248 template),
// used for W1 (EPI=2) and W2 (EPI=1). C[M,N] = epi(A[M,K] @ BT[N,K]^T + bias).
// 256x256 tile, BK=64, 8 waves (2M x 4N), wave tile 128x64, acc[8][4].
// LDS 128 KB: A/B x 2 dbuf x 2 halves (16 KB each: 128 rows x 64 k).
// Per K-tile: 4 phases {ds_read quadrant; issue 1 half of tile t+1 (2 glds);
// barrier; lgkmcnt(0); setprio(1)+16 MFMA+setprio(0); barrier}. Boundary:
// issue h0 of t+2 FIRST, then vmcnt(2) (outstanding = 8 of t+1 + 2 of t+2;
// retires exactly t+1) -- never drains to 0 in the main loop.
// WAR: buf[(t+2)&1] re-staged only after the closing barrier of tile t which
// read it. Staging/read = proven 16x32-chunk source-swizzle (0 conflicts).
// ---------------------------------------------------------------------------
#define MM8(MS,NS) do{ \
    __builtin_amdgcn_s_barrier(); \
    asm volatile("s_waitcnt lgkmcnt(0)" ::: "memory"); \
    __builtin_amdgcn_sched_barrier(0); \
    __builtin_amdgcn_s_setprio(1); \
    _Pragma("unroll") \
    for (int f = 0; f < 4; f++) { \
      acc[(MS)*4+f][(NS)*2+0] = __builtin_amdgcn_mfma_f32_16x16x32_bf16(af[f][0], bf[0][0], acc[(MS)*4+f][(NS)*2+0],0,0,0); \
      acc[(MS)*4+f][(NS)*2+0] = __builtin_amdgcn_mfma_f32_16x16x32_bf16(af[f][1], bf[0][1], acc[(MS)*4+f][(NS)*2+0],0,0,0); \
      acc[(MS)*4+f][(NS)*2+1] = __builtin_amdgcn_mfma_f32_16x16x32_bf16(af[f][0], bf[1][0], acc[(MS)*4+f][(NS)*2+1],0,0,0); \
      acc[(MS)*4+f][(NS)*2+1] = __builtin_amdgcn_mfma_f32_16x16x32_bf16(af[f][1], bf[1][1], acc[(MS)*4+f][(NS)*2+1],0,0,0); \
    } \
    __builtin_amdgcn_s_setprio(0); \
    __builtin_amdgcn_sched_barrier(0); \
    __builtin_amdgcn_s_barrier(); \
}while(0)

template<int EPI>
__launch_bounds__(512, 2)
__global__ void gemm8(const u16* __restrict__ A, const u16* __restrict__ BT,
                      const float* __restrict__ bias, u16* __restrict__ C,
                      int N, int K, int row0,
                      const u16* __restrict__ R0,
                      const float* __restrict__ g, const float* __restrict__ be,
                      const float* __restrict__ rmv, const float* __restrict__ rvv,
                      const float* __restrict__ alpha,
                      const float* __restrict__ saw, const float* __restrict__ sab) {
    __shared__ __align__(16) u16 SL[65536];   // 128 KB: A [0,32768), B [32768,65536)
    const int tid = threadIdx.x, wave = tid >> 6, lane = tid & 63;
    const int wm = wave >> 2, wn = wave & 3;  // 2M x 4N
    const int quad = lane >> 4, l16 = lane & 15;

    // XCD-aware bijective block swizzle (m204)
    const unsigned gx = gridDim.x;
    unsigned lin = blockIdx.y * gx + blockIdx.x;
    const unsigned nwg = gx * gridDim.y;
    const unsigned q8 = nwg >> 3, r8 = nwg & 7;
    const unsigned xcd = lin & 7, loc = lin >> 3;
    lin = (xcd < r8 ? xcd * (q8 + 1) : r8 * (q8 + 1) + (xcd - r8) * q8) + loc;
    const int m0 = (int)(lin / gx) * 256, n0 = (int)(lin % gx) * 256;

    const int T = K >> 6;   // K-tiles of 64 (K is 256 or 2048 -> T >= 4)

    // staging lane geometry (proven chunk swizzle: 16 rows x 32 k per 1 KB chunk)
    const int srow = lane >> 2;
    const int scol = (((lane & 3) ^ ((srow >> 1) & 3)) * 8);
    const int ci0 = wave * 2;

    auto issueHalf = [&](int mat, int h, int t) {
        const u16* src = (mat == 0) ? (A + (size_t)(m0 + h * 128) * K)
                                    : (BT + (size_t)(n0 + h * 128) * K);
        u16* dst = SL + mat * 32768 + (t & 1) * 16384 + h * 8192;
        #pragma unroll
        for (int i = 0; i < 2; i++) {
            const int ci = ci0 + i, rg = ci >> 1, kc = ci & 1;
            glds16(src + (size_t)(rg * 16 + srow) * K + t * 64 + kc * 32 + scol,
                   dst + kc * 4096 + rg * 512);
        }
    };

    const int cfrag = (quad ^ ((l16 >> 1) & 3)) * 8;
    f32x4 acc[8][4] = {};
    bf16x8 af[4][2], bf[2][2];

    // prologue: tile 0 fully + A-h0 of tile 1
    issueHalf(0, 0, 0); issueHalf(0, 1, 0); issueHalf(1, 0, 0); issueHalf(1, 1, 0);
    if (T > 1) { issueHalf(0, 0, 1); asm volatile("s_waitcnt vmcnt(2)" ::: "memory"); }
    else       {                     asm volatile("s_waitcnt vmcnt(0)" ::: "memory"); }
    __builtin_amdgcn_s_barrier();

    for (int t = 0; t < T; ++t) {
        const int c = t & 1;
        const bool nx = (t + 1 < T);
        const u16* Ab = SL + c * 16384 + wm * 8192;
        const u16* Bb = SL + 32768 + c * 16384 + (wn >> 1) * 8192;
        const int bcol = (wn & 1) * 64;

        auto rdAf = [&](int ms) {
            #pragma unroll
            for (int f = 0; f < 4; f++)
                #pragma unroll
                for (int kk = 0; kk < 2; kk++)
                    af[f][kk] = *(const bf16x8*)&Ab[kk * 4096 + (ms * 64 + f * 16 + l16) * 32 + cfrag];
        };
        auto rdBf = [&](int ns) {
            #pragma unroll
            for (int gg = 0; gg < 2; gg++)
                #pragma unroll
                for (int kk = 0; kk < 2; kk++)
                    bf[gg][kk] = *(const bf16x8*)&Bb[kk * 4096 + (bcol + ns * 32 + gg * 16 + l16) * 32 + cfrag];
        };

        rdAf(0); rdBf(0); if (nx) issueHalf(0, 1, t + 1); MM8(0, 0);
        rdBf(1);          if (nx) issueHalf(1, 0, t + 1); MM8(0, 1);
        rdAf(1);          if (nx) issueHalf(1, 1, t + 1); MM8(1, 1);
        rdBf(0);                                          MM8(1, 0);

        if (nx) {  // boundary: issue-first, then counted wait
            if (t + 2 < T) { issueHalf(0, 0, t + 2); asm volatile("s_waitcnt vmcnt(2)" ::: "memory"); }
            else           {                         asm volatile("s_waitcnt vmcnt(0)" ::: "memory"); }
            __builtin_amdgcn_s_barrier();
        }
    }

    // ---------------- epilogue ----------------
    const int dup = l16 & 1, pr = l16 >> 1;
    const float alphav = (EPI == 1) ? alpha[0] : 0.f;
    float biasv[4], k0p[4][2], k1p[4][2];
    #pragma unroll
    for (int j = 0; j < 4; j++) {
        biasv[j] = bias[n0 + wn * 64 + j * 16 + l16];
        if (EPI == 1) {
            #pragma unroll
            for (int p = 0; p < 2; p++) {
                const int col = n0 + wn * 64 + j * 16 + pr * 2 + p;
                const float sc = g[col] * rsqrtf(rvv[col] + 1e-5f);
                k1p[j][p] = sc + alphav;
                k0p[j][p] = be[col] - rmv[col] * sc;
            }
        }
    }
    const int r0i = 2 * dup, r1i = r0i + 1;

    #pragma unroll
    for (int i = 0; i < 8; i++) {
        const int rowb = m0 + wm * 128 + i * 16 + quad * 4;
        float swv4[4], sbv4[4];
        if (EPI == 2) {
            #pragma unroll
            for (int r = 0; r < 4; r++) {
                const int bidx = (row0 + rowb + r) / 196;
                swv4[r] = saw[bidx]; sbv4[r] = sab[bidx];
            }
        }
        #pragma unroll
        for (int j = 0; j < 4; j++) {
            float vv[4];
            #pragma unroll
            for (int r = 0; r < 4; r++) {
                float v = acc[i][j][r] + biasv[j];
                if (EPI == 2) {
                    const float w = fmaf(swv4[r], v, sbv4[r]);
                    v = v / (1.f + __expf(-w * v));
                }
                vv[r] = v;
            }
            float ot[4];
            #pragma unroll
            for (int r = 0; r < 4; r++) ot[r] = __shfl_xor(vv[r], 1, 64);
            float lo0 = dup ? ot[r0i] : vv[r0i], hi0 = dup ? vv[r0i] : ot[r0i];
            float lo1 = dup ? ot[r1i] : vv[r1i], hi1 = dup ? vv[r1i] : ot[r1i];
            if (EPI == 1) {
                const u16* rp = R0 + (size_t)(rowb + r0i) * N + (n0 + wn * 64 + j * 16 + pr * 2);
                const unsigned rd0 = *(const unsigned*)rp;
                const unsigned rd1 = *(const unsigned*)(rp + N);
                lo0 = fmaf(lo0 + b2f((u16)(rd0 & 0xffff)), k1p[j][0], k0p[j][0]);
                hi0 = fmaf(hi0 + b2f((u16)(rd0 >> 16)),    k1p[j][1], k0p[j][1]);
                lo1 = fmaf(lo1 + b2f((u16)(rd1 & 0xffff)), k1p[j][0], k0p[j][0]);
                hi1 = fmaf(hi1 + b2f((u16)(rd1 >> 16)),    k1p[j][1], k0p[j][1]);
            }
            u16* p = C + (size_t)(rowb + 2 * dup) * N + (n0 + wn * 64 + j * 16 + pr * 2);
            *(unsigned*)p       = cvtpk(lo0, hi0);
            *(unsigned*)(p + N) = cvtpk(lo1, hi1);
        }
    }
}

// ---------------------------------------------------------------------------
// gemm_bt: generic K GEMM (qkv EPI=0, proj EPI=1). R9 proven structure:
// 256x128 tile, BK=32, 8 waves (4M x 2N), 2-buffer 1-barrier K-loop.
// ---------------------------------------------------------------------------
template<int EPI>
__launch_bounds__(512, 4)
__global__ void gemm_bt(const u16* __restrict__ A, const u16* __restrict__ BT,
                        const float* __restrict__ bias, u16* __restrict__ C,
                        int M, int N, int K, int row0,
                        const u16* __restrict__ R0,
                        const float* __restrict__ g, const float* __restrict__ be,
                        const float* __restrict__ rmv, const float* __restrict__ rvv,
                        const float* __restrict__ alpha,
                        const float* __restrict__ saw, const float* __restrict__ sab) {
    __shared__ __align__(16) u16 SL[24576];  // 48 KB: A 2x8192, B 2x4096
    const int tid  = threadIdx.x;
    const int wave = tid >> 6, lane = tid & 63;
    const int wm = wave >> 1, wn = wave & 1;
    const int quad = lane >> 4, l16 = lane & 15;

    const unsigned gx = gridDim.x;
    unsigned lin = blockIdx.y * gx + blockIdx.x;
    const unsigned nwg = gx * gridDim.y;
    const unsigned q8 = nwg >> 3, r8 = nwg & 7;
    const unsigned xcd = lin & 7, loc = lin >> 3;
    lin = (xcd < r8 ? xcd * (q8 + 1) : r8 * (q8 + 1) + (xcd - r8) * q8) + loc;
    const int m0 = (int)(lin / gx) * 256, n0 = (int)(lin % gx) * 128;

    const int srow = lane >> 2;
    const int scol = (((lane & 3) ^ ((srow >> 1) & 3)) * 8);
    const size_t aoff0 = (size_t)(m0 + wave * 32 + srow) * K + scol;
    const size_t aoff1 = aoff0 + (size_t)16 * K;
    const size_t boff  = (size_t)(n0 + wave * 16 + srow) * K + scol;

    const int cfrag = (quad ^ ((l16 >> 1) & 3)) * 8;

    f32x4 acc[4][4] = {};
    const int niter = K >> 5;

    auto stage = [&](int buf, size_t kn) {
        glds16(A  + aoff0 + kn, SL + buf * 8192 + wave * 1024);
        glds16(A  + aoff1 + kn, SL + buf * 8192 + wave * 1024 + 512);
        glds16(BT + boff  + kn, SL + 16384 + buf * 4096 + wave * 512);
    };

    auto kstep = [&](int cur, int kt) {
        __syncthreads();
        if (kt + 1 < niter) stage(cur ^ 1, (size_t)(kt + 1) << 5);
        const u16* ab = SL + cur * 8192;
        const u16* bb = SL + 16384 + cur * 4096;
        bf16x8 af[4], bfr[4];
        #pragma unroll
        for (int i = 0; i < 4; i++)
            af[i] = *(const bf16x8*)&ab[(wm * 64 + i * 16 + l16) * 32 + cfrag];
        #pragma unroll
        for (int j = 0; j < 4; j++)
            bfr[j] = *(const bf16x8*)&bb[(wn * 64 + j * 16 + l16) * 32 + cfrag];
        #pragma unroll
        for (int i = 0; i < 4; i++)
            #pragma unroll
            for (int j = 0; j < 4; j++)
                acc[i][j] = __builtin_amdgcn_mfma_f32_16x16x32_bf16(af[i], bfr[j], acc[i][j], 0, 0, 0);
    };

    stage(0, 0);
    int kt = 0;
    for (; kt + 2 <= niter; kt += 2) { kstep(0, kt); kstep(1, kt + 1); }
    if (kt < niter) kstep(kt & 1, kt);

    __syncthreads();

    float alphav = 0.f;
    if (EPI == 1) alphav = alpha[0];

    float biasv[4], k0v[4], k1v[4];
    #pragma unroll
    for (int j = 0; j < 4; j++) {
        const int col = n0 + wn * 64 + j * 16 + l16;
        biasv[j] = bias[col];
        if (EPI == 1) {
            float sc = g[col] * rsqrtf(rvv[col] + 1e-5f);
            k1v[j] = sc + alphav;
            k0v[j] = be[col] - rmv[col] * sc;
        }
    }

    const int dup = l16 & 1;
    const int pr  = l16 >> 1;
    u16* Crow = C + (size_t)(m0 + wm * 64 + quad * 4 + 2 * dup) * N
                  + (n0 + wn * 64 + pr * 2);

    auto emit = [&]() {
        #pragma unroll
        for (int i = 0; i < 4; i++) {
            float swv4[4], sbv4[4];
            if (EPI == 2) {
                #pragma unroll
                for (int r = 0; r < 4; r++) {
                    const int row = row0 + m0 + wm * 64 + i * 16 + quad * 4 + r;
                    const int bidx = row / 196;
                    swv4[r] = saw[bidx]; sbv4[r] = sab[bidx];
                }
            }
            #pragma unroll
            for (int j = 0; j < 4; j++) {
                float vv[4];
                #pragma unroll
                for (int r = 0; r < 4; r++) {
                    float v = acc[i][j][r] + biasv[j];
                    if (EPI == 1) {
                        const int rowL = (wm & 1) * 64 + i * 16 + quad * 4 + r;
                        const int colp = wn * 64 + j * 16 + (l16 & ~1);
                        unsigned rd = *(const unsigned*)&SL[rowL * 128 + colp];
                        unsigned fb = dup ? (rd & 0xffff0000u) : (rd << 16);
                        union { unsigned u; float f; } cc; cc.u = fb;
                        float x = v + cc.f;
                        v = fmaf(x, k1v[j], k0v[j]);
                    } else if (EPI == 2) {
                        float w = fmaf(swv4[r], v, sbv4[r]);
                        v = v / (1.f + __expf(-w * v));
                    }
                    vv[r] = v;
                }
                unsigned D[4];
                #pragma unroll
                for (int r = 0; r < 4; r++) {
                    float o  = __shfl_xor(vv[r], 1, 64);
                    float lo = dup ? o : vv[r];
                    float hi = dup ? vv[r] : o;
                    D[r] = cvtpk(lo, hi);
                }
                unsigned s0 = dup ? D[2] : D[0];
                unsigned s1 = dup ? D[3] : D[1];
                u16* p = Crow + (size_t)i * 16 * N + j * 16;
                *(unsigned*)p       = s0;
                *(unsigned*)(p + N) = s1;
            }
        }
    };

    if (EPI == 1) {
        #pragma unroll
        for (int h = 0; h < 2; h++) {
            for (int c = tid; c < 2048; c += 512) {
                int row = c >> 4, colc = (c & 15) * 8;
                *(u16x8*)&SL[row * 128 + colc] =
                    *(const u16x8*)&R0[(size_t)(m0 + h * 128 + row) * N + n0 + colc];
            }
            __syncthreads();
            if ((wm >> 1) == h) emit();
            __syncthreads();
        }
    } else {
        emit();
    }
}

// ---------------------------------------------------------------------------
// MFMA flash attention: one block per (local b, h), 4 waves.
// V staging vectorized (u16x8 row reads + scalar transposed LDS writes).
// ---------------------------------------------------------------------------
__launch_bounds__(256)
__global__ void attn_kernel(const u16* __restrict__ qkv, u16* __restrict__ o) {
    __shared__ __align__(16) u16 Kb[224 * 32];
    __shared__ __align__(16) u16 Vt[32 * 232];
    __shared__ __align__(16) u16 Pl[4][16 * 232];
    const int tid  = threadIdx.x;
    const int wave = tid >> 6, lane = tid & 63;
    const int quad = lane >> 4, l16 = lane & 15;
    const int b = blockIdx.x >> 3, h = blockIdx.x & 7;
    const u16* qg = qkv + (size_t)b * 196 * 768 + h * 32;
    const float scale = 0.17677669529663687f; // 1/sqrt(32)

    for (int idx = tid; idx < 896; idx += 256) {
        int row = idx >> 2, dp = (idx & 3) * 8;
        u16x8 kv = {};
        if (row < 196) kv = *(const u16x8*)&qg[(size_t)row * 768 + 256 + dp];
        *(u16x8*)&Kb[row * 32 + dp] = kv;
    }
    for (int idx = tid; idx < 896; idx += 256) {
        int row = idx >> 2, dp = (idx & 3) * 8;
        u16x8 vv = {};
        if (row < 196) vv = *(const u16x8*)&qg[(size_t)row * 768 + 512 + dp];
        #pragma unroll
        for (int e = 0; e < 8; e++) Vt[(dp + e) * 232 + row] = vv[e];
    }
    for (int c = lane; c < 16 * 24; c += 64) {
        int m = c / 24, cc = 208 + (c % 24);
        Pl[wave][m * 232 + cc] = 0;
    }
    __syncthreads();

    for (int t = wave; t < 13; t += 4) {
        const int m0 = t * 16;
        bf16x8 aq = {};
        const int qrow = m0 + l16;
        if (qrow < 196) aq = *(const bf16x8*)&qg[(size_t)qrow * 768 + quad * 8];

        f32x4 s[13];
        #pragma unroll
        for (int ct = 0; ct < 13; ct++) {
            bf16x8 bk = *(const bf16x8*)&Kb[(ct * 16 + l16) * 32 + quad * 8];
            s[ct] = __builtin_amdgcn_mfma_f32_16x16x32_bf16(aq, bk, (f32x4){0.f, 0.f, 0.f, 0.f}, 0, 0, 0);
        }
        if (l16 >= 4) {
            #pragma unroll
            for (int r = 0; r < 4; r++) s[12][r] = -1e30f;
        }
        float mx[4] = {-1e30f, -1e30f, -1e30f, -1e30f};
        #pragma unroll
        for (int ct = 0; ct < 13; ct++)
            #pragma unroll
            for (int r = 0; r < 4; r++) mx[r] = fmaxf(mx[r], s[ct][r]);
        #pragma unroll
        for (int off = 1; off < 16; off <<= 1)
            #pragma unroll
            for (int r = 0; r < 4; r++) mx[r] = fmaxf(mx[r], __shfl_xor(mx[r], off, 64));
        float sum[4] = {0.f, 0.f, 0.f, 0.f};
        #pragma unroll
        for (int ct = 0; ct < 13; ct++) {
            #pragma unroll
            for (int r = 0; r < 4; r++) {
                float p = __expf((s[ct][r] - mx[r]) * scale);
                sum[r] += p;
                Pl[wave][(quad * 4 + r) * 232 + ct * 16 + l16] = f2b(p);
            }
        }
        #pragma unroll
        for (int off = 1; off < 16; off <<= 1)
            #pragma unroll
            for (int r = 0; r < 4; r++) sum[r] += __shfl_xor(sum[r], off, 64);
        float inv[4];
        #pragma unroll
        for (int r = 0; r < 4; r++) inv[r] = 1.f / sum[r];

        #pragma unroll
        for (int nt = 0; nt < 2; nt++) {
            f32x4 ao = {0.f, 0.f, 0.f, 0.f};
            #pragma unroll
            for (int kc = 0; kc < 7; kc++) {
                bf16x8 ap = *(const bf16x8*)&Pl[wave][l16 * 232 + kc * 32 + quad * 8];
                bf16x8 bv = *(const bf16x8*)&Vt[(nt * 16 + l16) * 232 + kc * 32 + quad * 8];
                ao = __builtin_amdgcn_mfma_f32_16x16x32_bf16(ap, bv, ao, 0, 0, 0);
            }
            #pragma unroll
            for (int r = 0; r < 4; r++) {
                const int gm = m0 + quad * 4 + r;
                if (gm < 196)
                    o[((size_t)b * 196 + gm) * 256 + h * 32 + nt * 16 + l16] = f2b(ao[r] * inv[r]);
            }
        }
    }
}

// ---------------------------------------------------------------------------
extern "C" void kernel_launch(void* const* d_in, const int* in_sizes, int n_in,
                              void* d_out, int out_size, void* d_ws, size_t ws_size,
                              hipStream_t stream) {
    const float* x      = (const float*)d_in[0];
    const float* Wqkv   = (const float*)d_in[1];
    const float* bqkv   = (const float*)d_in[2];
    const float* Wproj  = (const float*)d_in[3];
    const float* bproj  = (const float*)d_in[4];
    const float* W1     = (const float*)d_in[5];
    const float* b1     = (const float*)d_in[6];
    const float* W2     = (const float*)d_in[7];
    const float* b2     = (const float*)d_in[8];
    const float* saw    = (const float*)d_in[9];
    const float* sab    = (const float*)d_in[10];
    const float* alpha1 = (const float*)d_in[11];
    const float* g1     = (const float*)d_in[12];
    const float* be1    = (const float*)d_in[13];
    const float* rm1    = (const float*)d_in[14];
    const float* rv1    = (const float*)d_in[15];
    const float* alpha2 = (const float*)d_in[16];
    const float* g2     = (const float*)d_in[17];
    const float* be2    = (const float*)d_in[18];
    const float* rm2    = (const float*)d_in[19];
    const float* rv2    = (const float*)d_in[20];

    const int B = 256, Cc = 256, Np = 196, CM = 2048;
    const int M = B * Np; // 50176

    auto al = [](size_t s) { return (s + 255) & ~(size_t)255; };
    char* ws = (char*)d_ws;
    const size_t o_t0  = 0;
    const size_t o_t1  = o_t0 + al((size_t)M * Cc * 2);
    const size_t o_wq  = o_t1 + al((size_t)M * Cc * 2);
    const size_t o_wp  = o_wq + al((size_t)768 * Cc * 2);
    const size_t o_w1  = o_wp + al((size_t)Cc * Cc * 2);
    const size_t o_w2  = o_w1 + al((size_t)Cc * CM * 2);
    const size_t o_scr = o_w2 + al((size_t)CM * Cc * 2);
    const size_t S = (ws_size > o_scr) ? ws_size - o_scr : 0;

    u16* t0     = (u16*)(ws + o_t0);
    u16* t1b    = (u16*)(ws + o_t1);
    u16* WqkvT  = (u16*)(ws + o_wq);
    u16* WprojT = (u16*)(ws + o_wp);
    u16* W1T    = (u16*)(ws + o_w1);
    u16* W2T    = (u16*)(ws + o_w2);
    u16* scr    = (u16*)(ws + o_scr);
    u16* t2     = t0;            // alias: t0 dead after proj epilogue
    u16* obuf   = (u16*)d_out;   // bf16 scratch in f32 d_out; fully rewritten by final btrans
    float* out  = (float*)d_out;

    // chunk counts: M-chunks must stay multiples of 256.
    int nq = 1; while (nq < 4 && ((size_t)(M / nq) * 768 * 2) > S) nq *= 2;
    const int nf_opts[5] = {1, 2, 4, 14, 28};
    int nf = 28;
    for (int i = 0; i < 5; ++i) {
        if (((size_t)(M / nf_opts[i]) * CM * 2) <= S) { nf = nf_opts[i]; break; }
    }
    const int Mq = M / nq, Bq = B / nq;
    const int Mf = M / nf;

    dim3 tb(32, 8, 1);
    // x f32 [B][C][N] -> t0 bf16 [B][N][C]
    btrans_f2b<<<dim3((Np + 31) / 32, (Cc + 31) / 32, B), tb, 0, stream>>>(x, t0, Cc, Np);
    // weights f32 [K][N] -> bf16 [N][K]
    btrans_f2b<<<dim3(768 / 32, Cc / 32, 1), tb, 0, stream>>>(Wqkv,  WqkvT,  Cc, 768);
    btrans_f2b<<<dim3(Cc  / 32, Cc / 32, 1), tb, 0, stream>>>(Wproj, WprojT, Cc, Cc);
    btrans_f2b<<<dim3(CM  / 32, Cc / 32, 1), tb, 0, stream>>>(W1,    W1T,    Cc, CM);
    btrans_f2b<<<dim3(Cc  / 32, CM / 32, 1), tb, 0, stream>>>(W2,    W2T,    CM, Cc);

    // qkv + attention, chunked over batches
    for (int c = 0; c < nq; ++c) {
        gemm_bt<0><<<dim3(768 / 128, Mq / 256), 512, 0, stream>>>(
            t0 + (size_t)c * Mq * Cc, WqkvT, bqkv, scr, Mq, 768, Cc, 0,
            nullptr, nullptr, nullptr, nullptr, nullptr, nullptr, nullptr, nullptr);
        attn_kernel<<<dim3(Bq * 8), 256, 0, stream>>>(scr, obuf + (size_t)c * Mq * Cc);
    }

    // t1 = RepBN1(t0 + obuf @ Wproj + bproj)
    gemm_bt<1><<<dim3(Cc / 128, M / 256), 512, 0, stream>>>(
        obuf, WprojT, bproj, t1b, M, Cc, Cc, 0,
        t0, g1, be1, rm1, rv1, alpha1, nullptr, nullptr);

    // FFN: W1 and W2 on the 8-phase kernel (256x256 tiles)
    for (int c = 0; c < nf; ++c) {
        gemm8<2><<<dim3(CM / 256, Mf / 256), 512, 0, stream>>>(
            t1b + (size_t)c * Mf * Cc, W1T, b1, scr, CM, Cc, c * Mf,
            nullptr, nullptr, nullptr, nullptr, nullptr, nullptr, saw, sab);
        gemm8<1><<<dim3(Cc / 256, Mf / 256), 512, 0, stream>>>(
            scr, W2T, b2, t2 + (size_t)c * Mf * Cc, Cc, CM, 0,
            t1b + (size_t)c * Mf * Cc, g2, be2, rm2, rv2, alpha2, nullptr, nullptr);
    }

    // t2 bf16 [B][N][C] -> out f32 [B][C][N]
    btrans_b2f<<<dim3((Cc + 31) / 32, (Np + 31) / 32, B), tb, 0, stream>>>(t2, out, Np, Cc);
}